// Round 15
// baseline (2717.710 us; speedup 1.0000x reference)
//
#include <hip/hip_runtime.h>

#define NN    48
#define DD    16
#define HH    256
#define EE    2256
#define BB    32
#define NPRED 8
#define LSTR  56
#define PQS   1040                   // PQ per-node stride (floats), de-pow2

typedef __attribute__((ext_vector_type(4))) float f32x4;
typedef __attribute__((ext_vector_type(8))) short short8;

__device__ __forceinline__ float bf2f(unsigned short h) {
    union { unsigned u; float f; } v; v.u = ((unsigned)h) << 16; return v.f;
}
__device__ __forceinline__ unsigned short f2bf(float x) {
    union { float f; unsigned u; } v; v.f = x;
    unsigned r = v.u + 0x7fffu + ((v.u >> 16) & 1u);
    return (unsigned short)(r >> 16);
}
__device__ __forceinline__ unsigned perm_hi16(unsigned xB, unsigned xA, unsigned sel) {
    unsigned d;
    asm("v_perm_b32 %0, %1, %2, %3" : "=v"(d) : "v"(xB), "v"(xA), "s"(sel));
    return d;
}
struct Split3 { unsigned d0, d1, d2; };
__device__ __forceinline__ Split3 split2(float u0, float u1, unsigned sel)
{
    union F { float f; unsigned u; };
    Split3 o;
    F x0, x1; x0.f = u0; x1.f = u1;
    o.d0 = perm_hi16(x1.u, x0.u, sel);
    F h0a, h0b; h0a.u = x0.u & 0xffff0000u; h0b.u = x1.u & 0xffff0000u;
    F e0a, e0b; e0a.f = u0 - h0a.f; e0b.f = u1 - h0b.f;
    o.d1 = perm_hi16(e0b.u, e0a.u, sel);
    F h1a, h1b; h1a.u = e0a.u & 0xffff0000u; h1b.u = e0b.u & 0xffff0000u;
    F e1a, e1b; e1a.f = e0a.f - h1a.f; e1b.f = e0b.f - h1b.f;
    o.d2 = perm_hi16(e1b.u, e1a.u, sel);
    return o;
}
union PackA { unsigned u[4]; short8 s; };

// ---------------------------------------------------------------------------
// Setup (192 blocks) — unchanged (verified).
// ---------------------------------------------------------------------------
__global__ __launch_bounds__(256) void k_setup(
    const float* __restrict__ time_segs,
    const float* __restrict__ edge_types,
    const float* __restrict__ W1,      // (2,32,256)
    const float* __restrict__ W2,      // (2,256,256)
    const float* __restrict__ b1,      // (2,256)
    float* __restrict__ state,
    float* __restrict__ W1T,           // (2,256,32)
    unsigned short* __restrict__ W2f,  // 393216
    float* __restrict__ PQ,
    int* __restrict__ lists,
    int* __restrict__ counts)
{
    const int tid = blockIdx.x * 256 + threadIdx.x;
    const int NT = 192*256;
    for (int i = tid; i < BB*NN*DD; i += NT)
        state[i] = time_segs[i];
    for (int i = tid; i < 2*HH*32; i += NT) {
        const int t = i >> 13, r = i & 8191, h = r >> 5, f = r & 31;
        W1T[i] = W1[(t*32 + f)*HH + h];
    }
    for (int i = tid; i < 2*8*16*64*8; i += NT) {
        const int j  = i & 7, l = (i >> 3) & 63, nt = (i >> 9) & 15;
        const int kt = (i >> 13) & 7, t = (i >> 16) & 1;
        const int k = kt*32 + ((l >> 4) << 3) + j;
        const int n = nt*16 + (l & 15);
        const float w = W2[((size_t)t*HH + k)*HH + n];
        const unsigned short h0 = f2bf(w);  const float r1 = w  - bf2f(h0);
        const unsigned short h1 = f2bf(r1); const float r2 = r1 - bf2f(h1);
        const unsigned short h2 = f2bf(r2);
        const size_t rest = (size_t)kt*8192 + nt*512 + l*8 + j;
        W2f[(size_t)(t*3+0)*65536 + rest] = h0;
        W2f[(size_t)(t*3+1)*65536 + rest] = h1;
        W2f[(size_t)(t*3+2)*65536 + rest] = h2;
    }
    for (int i = tid; i < BB*NN*1024; i += NT) {
        const int c  = i & 255;
        const int pq = (i >> 8) & 1;
        const int t  = (i >> 9) & 1;
        const int nb = i >> 10;
        float v = pq ? b1[t*HH + c] : 0.f;
        #pragma unroll
        for (int f = 0; f < DD; ++f)
            v = fmaf(time_segs[nb*DD + f], W1[(t*32 + pq*16 + f)*HH + c], v);
        PQ[(size_t)nb*PQS + (i & 1023)] = v;
    }
    if (tid < BB*NN) {
        const int b = tid / NN;
        const int n = tid % NN;
        int* lst = lists + tid * LSTR;
        int c = 0;
        for (int s = 0; s < NN; ++s) {
            if (s == n) continue;
            const int e = s * 47 + (n > s ? n - 1 : n);
            if (edge_types[((size_t)b*EE + e)*3 + 1] > 0.5f) lst[c++] = s;
        }
        const int c1 = c;
        for (int s = 0; s < NN; ++s) {
            if (s == n) continue;
            const int e = s * 47 + (n > s ? n - 1 : n);
            if (edge_types[((size_t)b*EE + e)*3 + 2] > 0.5f) lst[c++] = s;
        }
        counts[tid*2 + 0] = c1;
        counts[tid*2 + 1] = c - c1;
        for (int i = c; i < LSTR; ++i) lst[i] = 0;
    }
}

// MFMA group for n-tile ii using B-buffer Bx over this section's tiles
#define MM(ii, Bx)                                                             \
    _Pragma("unroll")                                                          \
    for (int q2 = 0; q2 < 4; ++q2) {                                           \
        if (qb + q2 >= qloS && qb + q2 < qhiS) {                               \
            f32x4 a = acc[q2][ii];                                             \
            a = __builtin_amdgcn_mfma_f32_16x16x32_bf16(A[q2][2].s, Bx[0], a, 0, 0, 0); \
            a = __builtin_amdgcn_mfma_f32_16x16x32_bf16(A[q2][1].s, Bx[1], a, 0, 0, 0); \
            a = __builtin_amdgcn_mfma_f32_16x16x32_bf16(A[q2][0].s, Bx[2], a, 0, 0, 0); \
            a = __builtin_amdgcn_mfma_f32_16x16x32_bf16(A[q2][1].s, Bx[0], a, 0, 0, 0); \
            a = __builtin_amdgcn_mfma_f32_16x16x32_bf16(A[q2][0].s, Bx[1], a, 0, 0, 0); \
            a = __builtin_amdgcn_mfma_f32_16x16x32_bf16(A[q2][0].s, Bx[0], a, 0, 0, 0); \
            acc[q2][ii] = a;                                                   \
        }                                                                      \
    }

#define LOADB(Bx, nti)                                                         \
    _Pragma("unroll")                                                          \
    for (int p = 0; p < 3; ++p)                                                \
        Bx[p] = *(const short8*)(Wb + (size_t)p*65536 + (size_t)(nti)*512);

// ---------------------------------------------------------------------------
// Encoder v8: 1-wave blocks (64 thr), grid 6144 = (b, pair, tilehalf, ntq).
// Same per-wave work as v7, but: zero LDS, zero barriers, rowinfo in
// registers via shfl (64 lanes == 4 tiles x 16 rows), 4x finer scheduling
// granularity -> full co-residency (24 waves/CU of work, cap 32).
// ---------------------------------------------------------------------------
__global__ __launch_bounds__(64, 8) void k_enc(
    const int*   __restrict__ lists,
    const int*   __restrict__ counts,
    const float* __restrict__ PQ,
    const unsigned short* __restrict__ W2f,
    const float* __restrict__ b2,    // (2,256)
    float* __restrict__ nm)          // 2 x BB*NN*HH partials
{
    const int lb   = (blockIdx.x & 7)*768 + (blockIdx.x >> 3);  // XCD cluster
    const int b    = lb / 192;           // 4 batches per XCD
    const int rem  = lb % 192;
    const int pair = rem >> 3;
    const int half = (rem >> 2) & 1;     // tile-half
    const int ntq  = rem & 3;            // n-tile quad (cols ntq*64..)
    const int n0   = pair * 2;
    const int lane = threadIdx.x;        // 0..63
    const int c8   = (lane >> 4) * 8;
    const unsigned PSEL = 0x07060302u;

    // counts (same-address loads broadcast)
    const int c00 = counts[(b*NN + n0    )*2 + 0];
    const int c10 = counts[(b*NN + n0    )*2 + 1];
    const int c01 = counts[(b*NN + n0 + 1)*2 + 0];
    const int c11 = counts[(b*NN + n0 + 1)*2 + 1];
    const int tA  = c00 + c01, tB = c10 + c11;
    const int tAt = (tA + 15) >> 4, tBt = (tB + 15) >> 4;
    const int tiles = tAt + tBt;
    const int th = (tiles + 1) >> 1;
    const int qb = half ? th : 0;
    const int qe = half ? tiles : th;    // tiles in [qb,qe), <= 4

    // per-lane rowinfo: lane covers tile qb+(lane>>4), row lane&15
    int info;
    {
        const int myq = qb + (lane >> 4);
        const int r   = myq*16 + (lane & 15);
        int g = 4, src = 0;
        if (myq < qe) {
            if (r < tAt*16) {
                if (r < c00)     { src = lists[(b*NN + n0    )*LSTR + r];        g = 0; }
                else if (r < tA) { src = lists[(b*NN + n0 + 1)*LSTR + (r - c00)]; g = 1; }
            } else {
                const int s = r - tAt*16;
                if (s < c10)     { src = lists[(b*NN + n0    )*LSTR + c00 + s];        g = 2; }
                else if (s < tB) { src = lists[(b*NN + n0 + 1)*LSTR + c01 + (s - c10)]; g = 3; }
            }
        }
        info = src | (g << 8);
    }

    // per-lane P/Q base offsets for this half's tiles (src,node,type folded)
    int pbase[4], qbase[4];
    #pragma unroll
    for (int q2 = 0; q2 < 4; ++q2) {
        const int inf = __shfl(info, (q2 << 4) | (lane & 15));
        const int s2  = inf & 255;
        const int nd  = (inf >> 8) & 1;
        const int tq  = (qb + q2 >= tAt) ? 1 : 0;
        pbase[q2] = s2*PQS + tq*512;
        qbase[q2] = (n0 + nd)*PQS + tq*512 + 256;
    }

    f32x4 acc[4][4];
    #pragma unroll
    for (int q2 = 0; q2 < 4; ++q2)
        #pragma unroll
        for (int i = 0; i < 4; ++i)
            acc[q2][i] = (f32x4){0.f, 0.f, 0.f, 0.f};

    const float* PQb = PQ + (size_t)b*NN*PQS;

    #pragma unroll 1
    for (int kt = 0; kt < 8; ++kt) {
        const int kc = kt*32 + c8;
        // ---- fused A-build: all tiles (both types), one load volley ----
        PackA A[4][3];
        #pragma unroll
        for (int q2 = 0; q2 < 4; ++q2) {
            if (qb + q2 < qe) {
                const float* pr = PQb + pbase[q2] + kc;
                const float* qr = PQb + qbase[q2] + kc;
                const float4 Pa = *(const float4*)pr, Pb = *(const float4*)(pr+4);
                const float4 Qa = *(const float4*)qr, Qb = *(const float4*)(qr+4);
                const float u0 = fmaxf(Pa.x + Qa.x, 0.f);
                const float u1 = fmaxf(Pa.y + Qa.y, 0.f);
                const float u2 = fmaxf(Pa.z + Qa.z, 0.f);
                const float u3 = fmaxf(Pa.w + Qa.w, 0.f);
                const float u4 = fmaxf(Pb.x + Qb.x, 0.f);
                const float u5 = fmaxf(Pb.y + Qb.y, 0.f);
                const float u6 = fmaxf(Pb.z + Qb.z, 0.f);
                const float u7 = fmaxf(Pb.w + Qb.w, 0.f);
                const Split3 s0 = split2(u0, u1, PSEL);
                const Split3 s1 = split2(u2, u3, PSEL);
                const Split3 s2 = split2(u4, u5, PSEL);
                const Split3 s3 = split2(u6, u7, PSEL);
                A[q2][0].u[0]=s0.d0; A[q2][0].u[1]=s1.d0; A[q2][0].u[2]=s2.d0; A[q2][0].u[3]=s3.d0;
                A[q2][1].u[0]=s0.d1; A[q2][1].u[1]=s1.d1; A[q2][1].u[2]=s2.d1; A[q2][1].u[3]=s3.d1;
                A[q2][2].u[0]=s0.d2; A[q2][2].u[1]=s1.d2; A[q2][2].u[2]=s2.d2; A[q2][2].u[3]=s3.d2;
            }
        }
        // ---- MFMA: per type-section, static 2-deep B pipeline ----
        #pragma unroll
        for (int sec = 0; sec < 2; ++sec) {
            const int qloS = sec ? (tAt > qb ? tAt : qb) : qb;
            const int qhiS = sec ? qe : (tAt < qe ? tAt : qe);
            if (qloS >= qhiS) continue;
            const unsigned short* Wb = W2f + (size_t)sec*3*65536
                + (size_t)kt*8192 + (size_t)(ntq*4)*512 + (size_t)lane*8;
            short8 B0[3], B1[3];
            LOADB(B0, 0)
            LOADB(B1, 1)
            MM(0, B0)
            LOADB(B0, 2)
            MM(1, B1)
            LOADB(B1, 3)
            MM(2, B0)
            MM(3, B1)
        }
    }

    // ---- readout: relu(acc+b2), per-row node mask, shfl-reduce, store ----
    float b2v[2][4];
    #pragma unroll
    for (int t = 0; t < 2; ++t)
        #pragma unroll
        for (int i = 0; i < 4; ++i)
            b2v[t][i] = b2[t*HH + (ntq*4 + i)*16 + (lane & 15)];

    float p0[4], p1[4];
    #pragma unroll
    for (int i = 0; i < 4; ++i) { p0[i] = 0.f; p1[i] = 0.f; }
    #pragma unroll
    for (int q2 = 0; q2 < 4; ++q2) {
        if (qb + q2 < qe) {
            const bool secB = (qb + q2 >= tAt);
            int gv[4];
            #pragma unroll
            for (int rr = 0; rr < 4; ++rr)
                gv[rr] = __shfl(info, (q2 << 4) | ((lane >> 4)*4 + rr)) >> 8;
            #pragma unroll
            for (int i = 0; i < 4; ++i) {
                const float bias = secB ? b2v[1][i] : b2v[0][i];
                #pragma unroll
                for (int rr = 0; rr < 4; ++rr) {
                    const float v = fmaxf(acc[q2][i][rr] + bias, 0.f);
                    const bool valid = gv[rr] < 4;
                    p0[i] += (valid && !(gv[rr] & 1)) ? v : 0.f;
                    p1[i] += (valid &&  (gv[rr] & 1)) ? v : 0.f;
                }
            }
        }
    }
    float* nmh = nm + (size_t)half*BB*NN*HH;
    #pragma unroll
    for (int i = 0; i < 4; ++i) {
        float v0 = p0[i], v1 = p1[i];
        v0 += __shfl_xor(v0, 16); v0 += __shfl_xor(v0, 32);
        v1 += __shfl_xor(v1, 16); v1 += __shfl_xor(v1, 32);
        if ((lane >> 4) == 0) {
            nmh[((size_t)(b*NN + n0  ))*HH + (ntq*4 + i)*16 + lane] = v0;
            nmh[((size_t)(b*NN + n0+1))*HH + (ntq*4 + i)*16 + lane] = v1;
        }
    }
}

// ---------------------------------------------------------------------------
// Decoder: 4 rows/block (384 blocks), XCD-clustered, sums the 2 nm
// partials, fused next-step PQ production. Unchanged.
// ---------------------------------------------------------------------------
__global__ __launch_bounds__(256, 2) void k_dec(
    float* __restrict__ state,
    const float* __restrict__ nm,    // 2 partial buffers
    const float* __restrict__ W1, const float* __restrict__ b1,   // (272,256)
    const float* __restrict__ W2, const float* __restrict__ b2,   // (256,256)
    const float* __restrict__ W3, const float* __restrict__ b3,   // (256,16)
    const float* __restrict__ eW1T,  // (2,256,32)
    const float* __restrict__ eb1,   // (2,256)
    float* __restrict__ PQ,
    float* __restrict__ out, int step)
{
    const int lb   = (blockIdx.x & 7)*48 + (blockIdx.x >> 3);
    const int b    = lb / 12;
    const int row0 = (lb % 12) * 4;
    const int c    = threadIdx.x;
    const size_t NMSZ = (size_t)BB*NN*HH;

    __shared__ float in_s[4][272];
    __shared__ float d1s[4][HH];
    __shared__ float stn[4][DD];

    for (int i = c; i < 4*272; i += 256) {
        const int m = i / 272, k = i % 272;
        const int r = row0 + m;
        if (k < DD) {
            in_s[m][k] = state[((size_t)b*NN + r)*DD + k];
        } else {
            const size_t idx = ((size_t)b*NN + r)*HH + (k - DD);
            in_s[m][k] = nm[idx] + nm[NMSZ + idx];
        }
    }
    __syncthreads();

    float a0[4];
    {
        const float bb = b1[c];
        #pragma unroll
        for (int m = 0; m < 4; ++m) a0[m] = bb;
        #pragma unroll 2
        for (int k4 = 0; k4 < 68; ++k4) {
            const float* wr = W1 + (k4*4)*HH;
            const float w0=wr[c], w1_=wr[HH+c], w2_=wr[2*HH+c], w3=wr[3*HH+c];
            #pragma unroll
            for (int m = 0; m < 4; ++m) {
                const float4 h = *(const float4*)&in_s[m][k4*4];
                a0[m] = fmaf(h.x,w0, fmaf(h.y,w1_, fmaf(h.z,w2_, fmaf(h.w,w3, a0[m]))));
            }
        }
        #pragma unroll
        for (int m = 0; m < 4; ++m) d1s[m][c] = fmaxf(a0[m], 0.f);
    }
    __syncthreads();
    {
        const float bb = b2[c];
        #pragma unroll
        for (int m = 0; m < 4; ++m) a0[m] = bb;
        #pragma unroll 2
        for (int k4 = 0; k4 < 64; ++k4) {
            const float* wr = W2 + (k4*4)*HH;
            const float w0=wr[c], w1_=wr[HH+c], w2_=wr[2*HH+c], w3=wr[3*HH+c];
            #pragma unroll
            for (int m = 0; m < 4; ++m) {
                const float4 h = *(const float4*)&d1s[m][k4*4];
                a0[m] = fmaf(h.x,w0, fmaf(h.y,w1_, fmaf(h.z,w2_, fmaf(h.w,w3, a0[m]))));
            }
        }
        __syncthreads();
        #pragma unroll
        for (int m = 0; m < 4; ++m) in_s[m][c] = fmaxf(a0[m], 0.f);
    }
    __syncthreads();
    if (c < 64) {
        const int m = c >> 4, cc = c & 15;
        float a = b3[cc];
        #pragma unroll 4
        for (int k4 = 0; k4 < 64; ++k4) {
            const float4 h = *(const float4*)&in_s[m][k4*4];
            a += h.x*W3[(k4*4+0)*16+cc] + h.y*W3[(k4*4+1)*16+cc]
               + h.z*W3[(k4*4+2)*16+cc] + h.w*W3[(k4*4+3)*16+cc];
        }
        const int r = row0 + m;
        const float v = state[((size_t)b*NN + r)*DD + cc] + a;
        state[((size_t)b*NN + r)*DD + cc] = v;
        out[(((size_t)b*NPRED + step)*NN + r)*DD + cc] = v;
        stn[m][cc] = v;
    }
    __syncthreads();
    float4 sm[4][4];
    #pragma unroll
    for (int m = 0; m < 4; ++m)
        #pragma unroll
        for (int f4 = 0; f4 < 4; ++f4)
            sm[m][f4] = *(const float4*)&stn[m][f4*4];
    #pragma unroll
    for (int k = 0; k < 4; ++k) {
        const int combo = c + 256*k;
        const int cc = combo & 255;
        const int pq = (combo >> 8) & 1;
        const int t  = combo >> 9;
        const float* wc = eW1T + ((size_t)t*HH + cc)*32 + pq*16;
        float4 w[4];
        #pragma unroll
        for (int f4 = 0; f4 < 4; ++f4) w[f4] = ((const float4*)wc)[f4];
        const float bias = pq ? eb1[t*HH + cc] : 0.f;
        #pragma unroll
        for (int m = 0; m < 4; ++m) {
            float v = bias;
            #pragma unroll
            for (int f4 = 0; f4 < 4; ++f4) {
                const float4 s = sm[m][f4];
                v = fmaf(s.x,w[f4].x, fmaf(s.y,w[f4].y, fmaf(s.z,w[f4].z, fmaf(s.w,w[f4].w, v))));
            }
            PQ[(size_t)(b*NN + row0 + m)*PQS + t*512 + pq*256 + cc] = v;
        }
    }
}

// ---------------------------------------------------------------------------
extern "C" void kernel_launch(void* const* d_in, const int* in_sizes, int n_in,
                              void* d_out, int out_size, void* d_ws, size_t ws_size,
                              hipStream_t stream)
{
    const float* time_segs  = (const float*)d_in[0];
    const float* edge_types = (const float*)d_in[1];
    const float* enc_W1 = (const float*)d_in[4];
    const float* enc_b1 = (const float*)d_in[5];
    const float* enc_W2 = (const float*)d_in[6];
    const float* enc_b2 = (const float*)d_in[7];
    const float* dec_W1 = (const float*)d_in[8];
    const float* dec_b1 = (const float*)d_in[9];
    const float* dec_W2 = (const float*)d_in[10];
    const float* dec_b2 = (const float*)d_in[11];
    const float* out_W  = (const float*)d_in[12];
    const float* out_b  = (const float*)d_in[13];
    float* out = (float*)d_out;

    // workspace (~10.8 MB)
    float* state    = (float*)d_ws;                    // 24576 f
    float* nm       = state + BB*NN*DD;                // 786432 f (2 partials)
    float* W1T      = nm + 2*BB*NN*HH;                 // 16384 f
    unsigned short* W2f = (unsigned short*)(W1T + 2*HH*32);   // 393216 us
    int*   lists    = (int*)(W2f + 2*3*65536);         // 86016 i
    int*   counts   = lists + BB*NN*LSTR;              // 3072 i
    float* PQ       = (float*)(counts + BB*NN*2);      // 1597440 f

    k_setup<<<192, 256, 0, stream>>>(time_segs, edge_types, enc_W1, enc_W2,
                                     enc_b1, state, W1T, W2f, PQ, lists, counts);
    for (int stp = 0; stp < NPRED; ++stp) {
        k_enc<<<BB*NN*4, 64, 0, stream>>>(lists, counts, PQ, W2f,
                                          enc_b2, nm);
        k_dec<<<BB*12, 256, 0, stream>>>(state, nm,
                                         dec_W1, dec_b1, dec_W2, dec_b2,
                                         out_W, out_b, W1T, enc_b1, PQ, out, stp);
    }
}

// Round 16
// 706.553 us; speedup vs baseline: 3.8464x; 3.8464x over previous
//
#include <hip/hip_runtime.h>

#define NN    48
#define DD    16
#define HH    256
#define EE    2256
#define BB    32
#define NPRED 8
#define LSTR  56
#define PQS   1040                   // PQ per-node stride (floats), de-pow2

typedef __attribute__((ext_vector_type(4))) float f32x4;
typedef __attribute__((ext_vector_type(8))) short short8;

__device__ __forceinline__ float bf2f(unsigned short h) {
    union { unsigned u; float f; } v; v.u = ((unsigned)h) << 16; return v.f;
}
__device__ __forceinline__ unsigned short f2bf(float x) {
    union { float f; unsigned u; } v; v.f = x;
    unsigned r = v.u + 0x7fffu + ((v.u >> 16) & 1u);
    return (unsigned short)(r >> 16);
}
__device__ __forceinline__ unsigned perm_hi16(unsigned xB, unsigned xA, unsigned sel) {
    unsigned d;
    asm("v_perm_b32 %0, %1, %2, %3" : "=v"(d) : "v"(xB), "v"(xA), "s"(sel));
    return d;
}
struct Split3 { unsigned d0, d1, d2; };
__device__ __forceinline__ Split3 split2(float u0, float u1, unsigned sel)
{
    union F { float f; unsigned u; };
    Split3 o;
    F x0, x1; x0.f = u0; x1.f = u1;
    o.d0 = perm_hi16(x1.u, x0.u, sel);
    F h0a, h0b; h0a.u = x0.u & 0xffff0000u; h0b.u = x1.u & 0xffff0000u;
    F e0a, e0b; e0a.f = u0 - h0a.f; e0b.f = u1 - h0b.f;
    o.d1 = perm_hi16(e0b.u, e0a.u, sel);
    F h1a, h1b; h1a.u = e0a.u & 0xffff0000u; h1b.u = e0b.u & 0xffff0000u;
    F e1a, e1b; e1a.f = e0a.f - h1a.f; e1b.f = e0b.f - h1b.f;
    o.d2 = perm_hi16(e1b.u, e1a.u, sel);
    return o;
}
union PackA { unsigned u[4]; short8 s; };

// ---------------------------------------------------------------------------
// Setup (192 blocks) — unchanged (verified).
// ---------------------------------------------------------------------------
__global__ __launch_bounds__(256) void k_setup(
    const float* __restrict__ time_segs,
    const float* __restrict__ edge_types,
    const float* __restrict__ W1,      // (2,32,256)
    const float* __restrict__ W2,      // (2,256,256)
    const float* __restrict__ b1,      // (2,256)
    float* __restrict__ state,
    float* __restrict__ W1T,           // (2,256,32)
    unsigned short* __restrict__ W2f,  // 393216
    float* __restrict__ PQ,
    int* __restrict__ lists,
    int* __restrict__ counts)
{
    const int tid = blockIdx.x * 256 + threadIdx.x;
    const int NT = 192*256;
    for (int i = tid; i < BB*NN*DD; i += NT)
        state[i] = time_segs[i];
    for (int i = tid; i < 2*HH*32; i += NT) {
        const int t = i >> 13, r = i & 8191, h = r >> 5, f = r & 31;
        W1T[i] = W1[(t*32 + f)*HH + h];
    }
    for (int i = tid; i < 2*8*16*64*8; i += NT) {
        const int j  = i & 7, l = (i >> 3) & 63, nt = (i >> 9) & 15;
        const int kt = (i >> 13) & 7, t = (i >> 16) & 1;
        const int k = kt*32 + ((l >> 4) << 3) + j;
        const int n = nt*16 + (l & 15);
        const float w = W2[((size_t)t*HH + k)*HH + n];
        const unsigned short h0 = f2bf(w);  const float r1 = w  - bf2f(h0);
        const unsigned short h1 = f2bf(r1); const float r2 = r1 - bf2f(h1);
        const unsigned short h2 = f2bf(r2);
        const size_t rest = (size_t)kt*8192 + nt*512 + l*8 + j;
        W2f[(size_t)(t*3+0)*65536 + rest] = h0;
        W2f[(size_t)(t*3+1)*65536 + rest] = h1;
        W2f[(size_t)(t*3+2)*65536 + rest] = h2;
    }
    for (int i = tid; i < BB*NN*1024; i += NT) {
        const int c  = i & 255;
        const int pq = (i >> 8) & 1;
        const int t  = (i >> 9) & 1;
        const int nb = i >> 10;
        float v = pq ? b1[t*HH + c] : 0.f;
        #pragma unroll
        for (int f = 0; f < DD; ++f)
            v = fmaf(time_segs[nb*DD + f], W1[(t*32 + pq*16 + f)*HH + c], v);
        PQ[(size_t)nb*PQS + (i & 1023)] = v;
    }
    if (tid < BB*NN) {
        const int b = tid / NN;
        const int n = tid % NN;
        int* lst = lists + tid * LSTR;
        int c = 0;
        for (int s = 0; s < NN; ++s) {
            if (s == n) continue;
            const int e = s * 47 + (n > s ? n - 1 : n);
            if (edge_types[((size_t)b*EE + e)*3 + 1] > 0.5f) lst[c++] = s;
        }
        const int c1 = c;
        for (int s = 0; s < NN; ++s) {
            if (s == n) continue;
            const int e = s * 47 + (n > s ? n - 1 : n);
            if (edge_types[((size_t)b*EE + e)*3 + 2] > 0.5f) lst[c++] = s;
        }
        counts[tid*2 + 0] = c1;
        counts[tid*2 + 1] = c - c1;
        for (int i = c; i < LSTR; ++i) lst[i] = 0;
    }
}

// MFMA group for n-tile ii using B-buffer Bx over this section's tiles
#define MM(ii, Bx)                                                             \
    _Pragma("unroll")                                                          \
    for (int q2 = 0; q2 < 4; ++q2) {                                           \
        if (qb + q2 >= qloS && qb + q2 < qhiS) {                               \
            f32x4 a = acc[q2][ii];                                             \
            a = __builtin_amdgcn_mfma_f32_16x16x32_bf16(A[q2][2].s, Bx[0], a, 0, 0, 0); \
            a = __builtin_amdgcn_mfma_f32_16x16x32_bf16(A[q2][1].s, Bx[1], a, 0, 0, 0); \
            a = __builtin_amdgcn_mfma_f32_16x16x32_bf16(A[q2][0].s, Bx[2], a, 0, 0, 0); \
            a = __builtin_amdgcn_mfma_f32_16x16x32_bf16(A[q2][1].s, Bx[0], a, 0, 0, 0); \
            a = __builtin_amdgcn_mfma_f32_16x16x32_bf16(A[q2][0].s, Bx[1], a, 0, 0, 0); \
            a = __builtin_amdgcn_mfma_f32_16x16x32_bf16(A[q2][0].s, Bx[0], a, 0, 0, 0); \
            acc[q2][ii] = a;                                                   \
        }                                                                      \
    }

#define LOADB(Bx, nti)                                                         \
    _Pragma("unroll")                                                          \
    for (int p = 0; p < 3; ++p)                                                \
        Bx[p] = *(const short8*)(Wb + (size_t)p*65536 + (size_t)(nti)*512);

// ---------------------------------------------------------------------------
// Encoder v8b: 1-wave blocks (64 thr), grid 6144 = (b, pair, tilehalf, ntq).
// Zero LDS, zero barriers, rowinfo via shfl. launch_bounds(64,3): 3 waves/
// SIMD allows ~170 regs/wave (R15's (64,8) forced 64-reg cap -> total spill).
// ---------------------------------------------------------------------------
__global__ __launch_bounds__(64, 3) void k_enc(
    const int*   __restrict__ lists,
    const int*   __restrict__ counts,
    const float* __restrict__ PQ,
    const unsigned short* __restrict__ W2f,
    const float* __restrict__ b2,    // (2,256)
    float* __restrict__ nm)          // 2 x BB*NN*HH partials
{
    const int lb   = (blockIdx.x & 7)*768 + (blockIdx.x >> 3);  // XCD cluster
    const int b    = lb / 192;           // 4 batches per XCD
    const int rem  = lb % 192;
    const int pair = rem >> 3;
    const int half = (rem >> 2) & 1;     // tile-half
    const int ntq  = rem & 3;            // n-tile quad (cols ntq*64..)
    const int n0   = pair * 2;
    const int lane = threadIdx.x;        // 0..63
    const int c8   = (lane >> 4) * 8;
    const unsigned PSEL = 0x07060302u;

    // counts (same-address loads broadcast)
    const int c00 = counts[(b*NN + n0    )*2 + 0];
    const int c10 = counts[(b*NN + n0    )*2 + 1];
    const int c01 = counts[(b*NN + n0 + 1)*2 + 0];
    const int c11 = counts[(b*NN + n0 + 1)*2 + 1];
    const int tA  = c00 + c01, tB = c10 + c11;
    const int tAt = (tA + 15) >> 4, tBt = (tB + 15) >> 4;
    const int tiles = tAt + tBt;
    const int th = (tiles + 1) >> 1;
    const int qb = half ? th : 0;
    const int qe = half ? tiles : th;    // tiles in [qb,qe), <= 4

    // per-lane rowinfo: lane covers tile qb+(lane>>4), row lane&15
    int info;
    {
        const int myq = qb + (lane >> 4);
        const int r   = myq*16 + (lane & 15);
        int g = 4, src = 0;
        if (myq < qe) {
            if (r < tAt*16) {
                if (r < c00)     { src = lists[(b*NN + n0    )*LSTR + r];        g = 0; }
                else if (r < tA) { src = lists[(b*NN + n0 + 1)*LSTR + (r - c00)]; g = 1; }
            } else {
                const int s = r - tAt*16;
                if (s < c10)     { src = lists[(b*NN + n0    )*LSTR + c00 + s];        g = 2; }
                else if (s < tB) { src = lists[(b*NN + n0 + 1)*LSTR + c01 + (s - c10)]; g = 3; }
            }
        }
        info = src | (g << 8);
    }

    // per-lane P/Q base offsets for this half's tiles (src,node,type folded)
    int pbase[4], qbase[4];
    #pragma unroll
    for (int q2 = 0; q2 < 4; ++q2) {
        const int inf = __shfl(info, (q2 << 4) | (lane & 15));
        const int s2  = inf & 255;
        const int nd  = (inf >> 8) & 1;
        const int tq  = (qb + q2 >= tAt) ? 1 : 0;
        pbase[q2] = s2*PQS + tq*512;
        qbase[q2] = (n0 + nd)*PQS + tq*512 + 256;
    }

    f32x4 acc[4][4];
    #pragma unroll
    for (int q2 = 0; q2 < 4; ++q2)
        #pragma unroll
        for (int i = 0; i < 4; ++i)
            acc[q2][i] = (f32x4){0.f, 0.f, 0.f, 0.f};

    const float* PQb = PQ + (size_t)b*NN*PQS;

    #pragma unroll 1
    for (int kt = 0; kt < 8; ++kt) {
        const int kc = kt*32 + c8;
        // ---- fused A-build: all tiles (both types), one load volley ----
        PackA A[4][3];
        #pragma unroll
        for (int q2 = 0; q2 < 4; ++q2) {
            if (qb + q2 < qe) {
                const float* pr = PQb + pbase[q2] + kc;
                const float* qr = PQb + qbase[q2] + kc;
                const float4 Pa = *(const float4*)pr, Pb = *(const float4*)(pr+4);
                const float4 Qa = *(const float4*)qr, Qb = *(const float4*)(qr+4);
                const float u0 = fmaxf(Pa.x + Qa.x, 0.f);
                const float u1 = fmaxf(Pa.y + Qa.y, 0.f);
                const float u2 = fmaxf(Pa.z + Qa.z, 0.f);
                const float u3 = fmaxf(Pa.w + Qa.w, 0.f);
                const float u4 = fmaxf(Pb.x + Qb.x, 0.f);
                const float u5 = fmaxf(Pb.y + Qb.y, 0.f);
                const float u6 = fmaxf(Pb.z + Qb.z, 0.f);
                const float u7 = fmaxf(Pb.w + Qb.w, 0.f);
                const Split3 s0 = split2(u0, u1, PSEL);
                const Split3 s1 = split2(u2, u3, PSEL);
                const Split3 s2 = split2(u4, u5, PSEL);
                const Split3 s3 = split2(u6, u7, PSEL);
                A[q2][0].u[0]=s0.d0; A[q2][0].u[1]=s1.d0; A[q2][0].u[2]=s2.d0; A[q2][0].u[3]=s3.d0;
                A[q2][1].u[0]=s0.d1; A[q2][1].u[1]=s1.d1; A[q2][1].u[2]=s2.d1; A[q2][1].u[3]=s3.d1;
                A[q2][2].u[0]=s0.d2; A[q2][2].u[1]=s1.d2; A[q2][2].u[2]=s2.d2; A[q2][2].u[3]=s3.d2;
            }
        }
        // ---- MFMA: per type-section, static 2-deep B pipeline ----
        #pragma unroll
        for (int sec = 0; sec < 2; ++sec) {
            const int qloS = sec ? (tAt > qb ? tAt : qb) : qb;
            const int qhiS = sec ? qe : (tAt < qe ? tAt : qe);
            if (qloS >= qhiS) continue;
            const unsigned short* Wb = W2f + (size_t)sec*3*65536
                + (size_t)kt*8192 + (size_t)(ntq*4)*512 + (size_t)lane*8;
            short8 B0[3], B1[3];
            LOADB(B0, 0)
            LOADB(B1, 1)
            MM(0, B0)
            LOADB(B0, 2)
            MM(1, B1)
            LOADB(B1, 3)
            MM(2, B0)
            MM(3, B1)
        }
    }

    // ---- readout: relu(acc+b2), per-row node mask, shfl-reduce, store ----
    float b2v[2][4];
    #pragma unroll
    for (int t = 0; t < 2; ++t)
        #pragma unroll
        for (int i = 0; i < 4; ++i)
            b2v[t][i] = b2[t*HH + (ntq*4 + i)*16 + (lane & 15)];

    float p0[4], p1[4];
    #pragma unroll
    for (int i = 0; i < 4; ++i) { p0[i] = 0.f; p1[i] = 0.f; }
    #pragma unroll
    for (int q2 = 0; q2 < 4; ++q2) {
        if (qb + q2 < qe) {
            const bool secB = (qb + q2 >= tAt);
            int gv[4];
            #pragma unroll
            for (int rr = 0; rr < 4; ++rr)
                gv[rr] = __shfl(info, (q2 << 4) | ((lane >> 4)*4 + rr)) >> 8;
            #pragma unroll
            for (int i = 0; i < 4; ++i) {
                const float bias = secB ? b2v[1][i] : b2v[0][i];
                #pragma unroll
                for (int rr = 0; rr < 4; ++rr) {
                    const float v = fmaxf(acc[q2][i][rr] + bias, 0.f);
                    const bool valid = gv[rr] < 4;
                    p0[i] += (valid && !(gv[rr] & 1)) ? v : 0.f;
                    p1[i] += (valid &&  (gv[rr] & 1)) ? v : 0.f;
                }
            }
        }
    }
    float* nmh = nm + (size_t)half*BB*NN*HH;
    #pragma unroll
    for (int i = 0; i < 4; ++i) {
        float v0 = p0[i], v1 = p1[i];
        v0 += __shfl_xor(v0, 16); v0 += __shfl_xor(v0, 32);
        v1 += __shfl_xor(v1, 16); v1 += __shfl_xor(v1, 32);
        if ((lane >> 4) == 0) {
            nmh[((size_t)(b*NN + n0  ))*HH + (ntq*4 + i)*16 + lane] = v0;
            nmh[((size_t)(b*NN + n0+1))*HH + (ntq*4 + i)*16 + lane] = v1;
        }
    }
}

// ---------------------------------------------------------------------------
// Decoder: 4 rows/block (384 blocks), XCD-clustered, sums the 2 nm
// partials, fused next-step PQ production. Unchanged.
// ---------------------------------------------------------------------------
__global__ __launch_bounds__(256, 2) void k_dec(
    float* __restrict__ state,
    const float* __restrict__ nm,    // 2 partial buffers
    const float* __restrict__ W1, const float* __restrict__ b1,   // (272,256)
    const float* __restrict__ W2, const float* __restrict__ b2,   // (256,256)
    const float* __restrict__ W3, const float* __restrict__ b3,   // (256,16)
    const float* __restrict__ eW1T,  // (2,256,32)
    const float* __restrict__ eb1,   // (2,256)
    float* __restrict__ PQ,
    float* __restrict__ out, int step)
{
    const int lb   = (blockIdx.x & 7)*48 + (blockIdx.x >> 3);
    const int b    = lb / 12;
    const int row0 = (lb % 12) * 4;
    const int c    = threadIdx.x;
    const size_t NMSZ = (size_t)BB*NN*HH;

    __shared__ float in_s[4][272];
    __shared__ float d1s[4][HH];
    __shared__ float stn[4][DD];

    for (int i = c; i < 4*272; i += 256) {
        const int m = i / 272, k = i % 272;
        const int r = row0 + m;
        if (k < DD) {
            in_s[m][k] = state[((size_t)b*NN + r)*DD + k];
        } else {
            const size_t idx = ((size_t)b*NN + r)*HH + (k - DD);
            in_s[m][k] = nm[idx] + nm[NMSZ + idx];
        }
    }
    __syncthreads();

    float a0[4];
    {
        const float bb = b1[c];
        #pragma unroll
        for (int m = 0; m < 4; ++m) a0[m] = bb;
        #pragma unroll 2
        for (int k4 = 0; k4 < 68; ++k4) {
            const float* wr = W1 + (k4*4)*HH;
            const float w0=wr[c], w1_=wr[HH+c], w2_=wr[2*HH+c], w3=wr[3*HH+c];
            #pragma unroll
            for (int m = 0; m < 4; ++m) {
                const float4 h = *(const float4*)&in_s[m][k4*4];
                a0[m] = fmaf(h.x,w0, fmaf(h.y,w1_, fmaf(h.z,w2_, fmaf(h.w,w3, a0[m]))));
            }
        }
        #pragma unroll
        for (int m = 0; m < 4; ++m) d1s[m][c] = fmaxf(a0[m], 0.f);
    }
    __syncthreads();
    {
        const float bb = b2[c];
        #pragma unroll
        for (int m = 0; m < 4; ++m) a0[m] = bb;
        #pragma unroll 2
        for (int k4 = 0; k4 < 64; ++k4) {
            const float* wr = W2 + (k4*4)*HH;
            const float w0=wr[c], w1_=wr[HH+c], w2_=wr[2*HH+c], w3=wr[3*HH+c];
            #pragma unroll
            for (int m = 0; m < 4; ++m) {
                const float4 h = *(const float4*)&d1s[m][k4*4];
                a0[m] = fmaf(h.x,w0, fmaf(h.y,w1_, fmaf(h.z,w2_, fmaf(h.w,w3, a0[m]))));
            }
        }
        __syncthreads();
        #pragma unroll
        for (int m = 0; m < 4; ++m) in_s[m][c] = fmaxf(a0[m], 0.f);
    }
    __syncthreads();
    if (c < 64) {
        const int m = c >> 4, cc = c & 15;
        float a = b3[cc];
        #pragma unroll 4
        for (int k4 = 0; k4 < 64; ++k4) {
            const float4 h = *(const float4*)&in_s[m][k4*4];
            a += h.x*W3[(k4*4+0)*16+cc] + h.y*W3[(k4*4+1)*16+cc]
               + h.z*W3[(k4*4+2)*16+cc] + h.w*W3[(k4*4+3)*16+cc];
        }
        const int r = row0 + m;
        const float v = state[((size_t)b*NN + r)*DD + cc] + a;
        state[((size_t)b*NN + r)*DD + cc] = v;
        out[(((size_t)b*NPRED + step)*NN + r)*DD + cc] = v;
        stn[m][cc] = v;
    }
    __syncthreads();
    float4 sm[4][4];
    #pragma unroll
    for (int m = 0; m < 4; ++m)
        #pragma unroll
        for (int f4 = 0; f4 < 4; ++f4)
            sm[m][f4] = *(const float4*)&stn[m][f4*4];
    #pragma unroll
    for (int k = 0; k < 4; ++k) {
        const int combo = c + 256*k;
        const int cc = combo & 255;
        const int pq = (combo >> 8) & 1;
        const int t  = combo >> 9;
        const float* wc = eW1T + ((size_t)t*HH + cc)*32 + pq*16;
        float4 w[4];
        #pragma unroll
        for (int f4 = 0; f4 < 4; ++f4) w[f4] = ((const float4*)wc)[f4];
        const float bias = pq ? eb1[t*HH + cc] : 0.f;
        #pragma unroll
        for (int m = 0; m < 4; ++m) {
            float v = bias;
            #pragma unroll
            for (int f4 = 0; f4 < 4; ++f4) {
                const float4 s = sm[m][f4];
                v = fmaf(s.x,w[f4].x, fmaf(s.y,w[f4].y, fmaf(s.z,w[f4].z, fmaf(s.w,w[f4].w, v))));
            }
            PQ[(size_t)(b*NN + row0 + m)*PQS + t*512 + pq*256 + cc] = v;
        }
    }
}

// ---------------------------------------------------------------------------
extern "C" void kernel_launch(void* const* d_in, const int* in_sizes, int n_in,
                              void* d_out, int out_size, void* d_ws, size_t ws_size,
                              hipStream_t stream)
{
    const float* time_segs  = (const float*)d_in[0];
    const float* edge_types = (const float*)d_in[1];
    const float* enc_W1 = (const float*)d_in[4];
    const float* enc_b1 = (const float*)d_in[5];
    const float* enc_W2 = (const float*)d_in[6];
    const float* enc_b2 = (const float*)d_in[7];
    const float* dec_W1 = (const float*)d_in[8];
    const float* dec_b1 = (const float*)d_in[9];
    const float* dec_W2 = (const float*)d_in[10];
    const float* dec_b2 = (const float*)d_in[11];
    const float* out_W  = (const float*)d_in[12];
    const float* out_b  = (const float*)d_in[13];
    float* out = (float*)d_out;

    // workspace (~10.8 MB)
    float* state    = (float*)d_ws;                    // 24576 f
    float* nm       = state + BB*NN*DD;                // 786432 f (2 partials)
    float* W1T      = nm + 2*BB*NN*HH;                 // 16384 f
    unsigned short* W2f = (unsigned short*)(W1T + 2*HH*32);   // 393216 us
    int*   lists    = (int*)(W2f + 2*3*65536);         // 86016 i
    int*   counts   = lists + BB*NN*LSTR;              // 3072 i
    float* PQ       = (float*)(counts + BB*NN*2);      // 1597440 f

    k_setup<<<192, 256, 0, stream>>>(time_segs, edge_types, enc_W1, enc_W2,
                                     enc_b1, state, W1T, W2f, PQ, lists, counts);
    for (int stp = 0; stp < NPRED; ++stp) {
        k_enc<<<BB*NN*4, 64, 0, stream>>>(lists, counts, PQ, W2f,
                                          enc_b2, nm);
        k_dec<<<BB*12, 256, 0, stream>>>(state, nm,
                                         dec_W1, dec_b1, dec_W2, dec_b2,
                                         out_W, out_b, W1T, enc_b1, PQ, out, stp);
    }
}